// Round 1
// baseline (4113.827 us; speedup 1.0000x reference)
//
#include <hip/hip_runtime.h>
#include <hip/hip_bf16.h>

#define EB 16   // edges per 32-lane group (serial batch)

__device__ __forceinline__ float rcp_(float v){ return __builtin_amdgcn_rcpf(v); }
__device__ __forceinline__ float sigm_(float v){ return rcp_(1.0f + __expf(-v)); }
__device__ __forceinline__ float tanh_(float v){
    v = fminf(v, 15.0f);
    float t = __expf(2.0f * v);
    return (t - 1.0f) * rcp_(t + 1.0f);
}

// ---------------- kernel 1: coor = relu(x@W1^T)@W2^T  [N,32] ----------------
__global__ __launch_bounds__(256) void coor_kernel(
    const float* __restrict__ x, const float* __restrict__ w1,
    const float* __restrict__ w2, float* __restrict__ coor, int N)
{
    __shared__ float sW1[96];
    __shared__ float sW2[1024];
    const int tid = threadIdx.x;
    if (tid < 96) sW1[tid] = w1[tid];
    for (int i = tid; i < 1024; i += 256) sW2[i] = w2[i];
    __syncthreads();
    int n = blockIdx.x * 256 + tid;
    if (n >= N) return;
    const float x0 = x[n*3+0], x1 = x[n*3+1], x2 = x[n*3+2];
    float h[32];
#pragma unroll
    for (int k = 0; k < 32; ++k)
        h[k] = fmaxf(sW1[k*3+0]*x0 + sW1[k*3+1]*x1 + sW1[k*3+2]*x2, 0.0f);
    float* cp = coor + (size_t)n * 32;
#pragma unroll
    for (int j4 = 0; j4 < 8; ++j4) {
        float4 o;
        float* oc = (float*)&o;
#pragma unroll
        for (int q = 0; q < 4; ++q) {
            const int j = j4*4 + q;
            float a = 0.f;
#pragma unroll
            for (int k = 0; k < 32; ++k) a += sW2[j*32+k]*h[k];
            oc[q] = a;
        }
        *(float4*)(cp + j4*4) = o;
    }
}

// ---------------- kernel 2: fused bi-LSTM + message MLP + scatter ----------------
// layout: 256 threads = 8 groups of 32 lanes; each group serially handles EB edges.
// lane j owns hidden unit j: Whh gate rows {j,32+j,64+j,96+j} live in registers.
// h is shared within the group through a 96-float LDS buffer (broadcast reads).

__device__ __forceinline__ float lstm_edge(
    const float* __restrict__ tp,        // edge_traj + e*48
    const float wr[4][32], const float wi[4][6], const float bb[4],
    float* __restrict__ shb, int j, bool rev)
{
    float h = 0.f, c = 0.f;
    const float* xp = rev ? tp + 42 : tp;
    const int stp = rev ? -6 : 6;
    for (int t = 0; t < 8; ++t, xp += stp) {
        const float2 xa = *(const float2*)(xp);
        const float2 xb = *(const float2*)(xp + 2);
        const float2 xc = *(const float2*)(xp + 4);
        float gg[4];
#pragma unroll
        for (int g = 0; g < 4; ++g)
            gg[g] = bb[g] + wi[g][0]*xa.x + wi[g][1]*xa.y + wi[g][2]*xb.x
                  + wi[g][3]*xb.y + wi[g][4]*xc.x + wi[g][5]*xc.y;
        shb[j] = h;                       // share h across the group (intra-wave)
#pragma unroll
        for (int k = 0; k < 32; k += 4) {
            const float4 hv = *(const float4*)(shb + k);   // broadcast read
#pragma unroll
            for (int g = 0; g < 4; ++g)
                gg[g] += hv.x*wr[g][k] + hv.y*wr[g][k+1] + hv.z*wr[g][k+2] + hv.w*wr[g][k+3];
        }
        const float ig = sigm_(gg[0]);
        const float fg = sigm_(gg[1]);
        const float gt = tanh_(gg[2]);
        const float og = sigm_(gg[3]);
        c = fg*c + ig*gt;
        h = og * tanh_(c);
    }
    return c;
}

__device__ __forceinline__ void load_dir_weights(
    const float* __restrict__ w_hh, const float* __restrict__ w_ih,
    const float* __restrict__ b_ih, const float* __restrict__ b_hh,
    int j, float wr[4][32], float wi[4][6], float bb[4])
{
#pragma unroll
    for (int g = 0; g < 4; ++g) {
        const float* wp = w_hh + (g*32 + j)*32;
#pragma unroll
        for (int k = 0; k < 32; k += 4) {
            const float4 v = *(const float4*)(wp + k);
            wr[g][k] = v.x; wr[g][k+1] = v.y; wr[g][k+2] = v.z; wr[g][k+3] = v.w;
        }
        const float* ip = w_ih + (g*32 + j)*6;
#pragma unroll
        for (int k = 0; k < 6; ++k) wi[g][k] = ip[k];
        bb[g] = b_ih[g*32+j] + b_hh[g*32+j];
    }
}

__global__ __launch_bounds__(256, 2) void lstm_msg_kernel(
    const float* __restrict__ edge_traj,
    const float* __restrict__ w_ih_f, const float* __restrict__ w_hh_f,
    const float* __restrict__ b_ih_f, const float* __restrict__ b_hh_f,
    const float* __restrict__ w_ih_b, const float* __restrict__ w_hh_b,
    const float* __restrict__ b_ih_b, const float* __restrict__ b_hh_b,
    const float* __restrict__ nn2_w1, const float* __restrict__ nn2_w2,
    const int* __restrict__ edge_index,
    const float* __restrict__ coor,
    float* __restrict__ agg, int E)
{
    __shared__ float sbuf[8][96];
    __shared__ float cbuf[8][EB][32];   // c_f, then 0.5*(c_f+c_b)
    const int tid = threadIdx.x;
    const int j   = tid & 31;
    const int grp = tid >> 5;
    float* shb = &sbuf[grp][0];
    const long e0 = ((long)blockIdx.x * 8 + grp) * EB;

    float wr[4][32], wi[4][6], bb[4];

    // ---- forward direction
    load_dir_weights(w_hh_f, w_ih_f, b_ih_f, b_hh_f, j, wr, wi, bb);
    for (int i = 0; i < EB; ++i) {
        const long e = e0 + i;
        if (e < E)
            cbuf[grp][i][j] = lstm_edge(edge_traj + e*48, wr, wi, bb, shb, j, false);
    }
    // ---- backward direction
    load_dir_weights(w_hh_b, w_ih_b, b_ih_b, b_hh_b, j, wr, wi, bb);
    for (int i = 0; i < EB; ++i) {
        const long e = e0 + i;
        if (e < E) {
            const float cb = lstm_edge(edge_traj + e*48, wr, wi, bb, shb, j, true);
            cbuf[grp][i][j] = 0.5f * (cbuf[grp][i][j] + cb);
        }
    }
    // ---- message MLP + scatter
    float w1r[96], w2r[32];
#pragma unroll
    for (int k = 0; k < 96; k += 4) {
        const float4 v = *(const float4*)(nn2_w1 + j*96 + k);
        w1r[k] = v.x; w1r[k+1] = v.y; w1r[k+2] = v.z; w1r[k+3] = v.w;
    }
#pragma unroll
    for (int k = 0; k < 32; k += 4) {
        const float4 v = *(const float4*)(nn2_w2 + j*32 + k);
        w2r[k] = v.x; w2r[k+1] = v.y; w2r[k+2] = v.z; w2r[k+3] = v.w;
    }
    for (int i = 0; i < EB; ++i) {
        const long e = e0 + i;
        if (e >= E) continue;
        const int src = edge_index[e];
        const int dst = edge_index[E + e];
        shb[j]      = coor[(size_t)dst*32 + j];
        shb[32 + j] = coor[(size_t)src*32 + j];
        shb[64 + j] = cbuf[grp][i][j];
        float hacc = 0.f;
#pragma unroll
        for (int k = 0; k < 96; k += 4) {
            const float4 v = *(const float4*)(shb + k);
            hacc += v.x*w1r[k] + v.y*w1r[k+1] + v.z*w1r[k+2] + v.w*w1r[k+3];
        }
        hacc = fmaxf(hacc, 0.f);
        shb[j] = hacc;                    // safe: wave-lockstep, reads above done
        float macc = 0.f;
#pragma unroll
        for (int k = 0; k < 32; k += 4) {
            const float4 v = *(const float4*)(shb + k);
            macc += v.x*w2r[k] + v.y*w2r[k+1] + v.z*w2r[k+2] + v.w*w2r[k+3];
        }
        atomicAdd(agg + (size_t)dst*32 + j, macc);
    }
}

// ---------------- kernel 3: s32[k] = sum_n relu(agg[n]@nn_w1^T)[k] ----------------
__global__ __launch_bounds__(256) void agg_kernel(
    const float* __restrict__ agg, const float* __restrict__ nn_w1,
    float* __restrict__ s32, int N)
{
    __shared__ float sW[1024];
    const int tid = threadIdx.x;
    for (int i = tid; i < 1024; i += 256) sW[i] = nn_w1[i];
    __syncthreads();
    const int n = blockIdx.x*256 + tid;
    float h[32];
    if (n < N) {
        float a[32];
        const float4* ap = (const float4*)(agg + (size_t)n*32);
#pragma unroll
        for (int k4 = 0; k4 < 8; ++k4) {
            const float4 v = ap[k4];
            a[k4*4]=v.x; a[k4*4+1]=v.y; a[k4*4+2]=v.z; a[k4*4+3]=v.w;
        }
#pragma unroll
        for (int jj = 0; jj < 32; ++jj) {
            float acc = 0.f;
#pragma unroll
            for (int k = 0; k < 32; ++k) acc += sW[jj*32+k]*a[k];
            h[jj] = fmaxf(acc, 0.f);
        }
    } else {
#pragma unroll
        for (int jj = 0; jj < 32; ++jj) h[jj] = 0.f;
    }
#pragma unroll
    for (int m = 1; m < 64; m <<= 1) {
#pragma unroll
        for (int k = 0; k < 32; ++k) h[k] += __shfl_xor(h[k], m, 64);
    }
    if ((tid & 63) == 0) {
#pragma unroll
        for (int k = 0; k < 32; ++k) atomicAdd(s32 + k, h[k]);
    }
}

// ---------------- kernel 4: out[o] = nn_w2[o,:] . s32 ----------------
__global__ void final_kernel(const float* __restrict__ nn_w2,
                             const float* __restrict__ s32, float* __restrict__ out)
{
    const int o = threadIdx.x;   // 64
    float acc = 0.f;
#pragma unroll
    for (int k = 0; k < 32; ++k) acc += nn_w2[o*32+k] * s32[k];
    out[o] = acc;
}

extern "C" void kernel_launch(void* const* d_in, const int* in_sizes, int n_in,
                              void* d_out, int out_size, void* d_ws, size_t ws_size,
                              hipStream_t stream)
{
    const float* x         = (const float*)d_in[0];
    const float* edge_traj = (const float*)d_in[1];
    const float* w_ih_f    = (const float*)d_in[2];
    const float* w_hh_f    = (const float*)d_in[3];
    const float* b_ih_f    = (const float*)d_in[4];
    const float* b_hh_f    = (const float*)d_in[5];
    const float* w_ih_b    = (const float*)d_in[6];
    const float* w_hh_b    = (const float*)d_in[7];
    const float* b_ih_b    = (const float*)d_in[8];
    const float* b_hh_b    = (const float*)d_in[9];
    const float* coor_w1   = (const float*)d_in[10];
    const float* coor_w2   = (const float*)d_in[11];
    const float* nn2_w1    = (const float*)d_in[12];
    const float* nn2_w2    = (const float*)d_in[13];
    const float* nn_w1     = (const float*)d_in[14];
    const float* nn_w2     = (const float*)d_in[15];
    const int* edge_index  = (const int*)d_in[16];
    const int N = in_sizes[0] / 3;
    const int E = in_sizes[16] / 2;

    float* coor = (float*)d_ws;
    float* agg  = coor + (size_t)N * 32;
    float* s32  = agg + (size_t)N * 32;

    hipMemsetAsync(agg, 0, ((size_t)N*32 + 64) * sizeof(float), stream);

    coor_kernel<<<(N + 255)/256, 256, 0, stream>>>(x, coor_w1, coor_w2, coor, N);

    const long groups = ((long)E + EB - 1) / EB;
    const int  blocks = (int)((groups + 7) / 8);
    lstm_msg_kernel<<<blocks, 256, 0, stream>>>(edge_traj,
        w_ih_f, w_hh_f, b_ih_f, b_hh_f,
        w_ih_b, w_hh_b, b_ih_b, b_hh_b,
        nn2_w1, nn2_w2, edge_index, coor, agg, E);

    agg_kernel<<<(N + 255)/256, 256, 0, stream>>>(agg, nn_w1, s32, N);
    final_kernel<<<1, 64, 0, stream>>>(nn_w2, s32, (float*)d_out);
}

// Round 4
// 1444.262 us; speedup vs baseline: 2.8484x; 2.8484x over previous
//
#include <hip/hip_runtime.h>
#include <hip/hip_bf16.h>

typedef __attribute__((ext_vector_type(8))) short  bf16x8;
typedef __attribute__((ext_vector_type(4))) float  f32x4;

#define TPW 4   // 16-edge tiles per wave

__device__ __forceinline__ float rcp_(float v){ return __builtin_amdgcn_rcpf(v); }
__device__ __forceinline__ float exp2_(float v){ return __builtin_amdgcn_exp2f(v); }
__device__ __forceinline__ float sigm_(float v){
    return rcp_(1.0f + exp2_(v * -1.442695041f));
}
__device__ __forceinline__ float tanh_(float v){
    float vc = fminf(v, 15.0f);
    float t = exp2_(vc * 2.885390082f);
    return (t - 1.0f) * rcp_(t + 1.0f);
}
__device__ __forceinline__ unsigned short bf16b(float f){
    unsigned u = __float_as_uint(f);
    u += 0x7FFF + ((u >> 16) & 1);
    return (unsigned short)(u >> 16);
}
__device__ __forceinline__ unsigned pack2(float lo, float hi){
    return (unsigned)bf16b(lo) | ((unsigned)bf16b(hi) << 16);
}

union U4 { bf16x8 v; unsigned u[4]; };

__device__ __forceinline__ bf16x8 ldw8(const float* __restrict__ p){
    const float4 a = *(const float4*)p;
    const float4 b = *(const float4*)(p + 4);
    U4 r;
    r.u[0] = pack2(a.x, a.y); r.u[1] = pack2(a.z, a.w);
    r.u[2] = pack2(b.x, b.y); r.u[3] = pack2(b.z, b.w);
    return r.v;
}

// [Wih | bias | 0] fragment: k=0..5 features, k=6 bias, k=7 zero; lanes q>0 all zero
__device__ __forceinline__ bf16x8 ldih(const float* __restrict__ wih,
                                       const float* __restrict__ bi,
                                       const float* __restrict__ bh,
                                       int row, int lq){
    U4 r;
    r.u[0] = r.u[1] = r.u[2] = r.u[3] = 0u;
    if (lq == 0) {
        const float* p = wih + row * 6;
        r.u[0] = pack2(p[0], p[1]);
        r.u[1] = pack2(p[2], p[3]);
        r.u[2] = pack2(p[4], p[5]);
        r.u[3] = pack2(bi[row] + bh[row], 0.0f);
    }
    return r.v;
}

// Redistribute per-edge 32-vector from D layout (lane q holds positions
// {4q..4q+3} as W0/W1 [lo] and {16+4q..16+4q+3} as W2/W3 [hi]) to B-frag
// layout (lane q needs positions {8q..8q+7}). Sources: first 4 from lane
// 2*(q&1), next 4 from that +1; take lo words iff TARGET q<2 (select at
// target — a source-side select is wrong, each source serves a lo-reader
// AND a hi-reader in the same shfl).
__device__ __forceinline__ void redist(unsigned W0, unsigned W1, unsigned W2, unsigned W3,
                                       int sa, int sb, bool lo, unsigned out[4]){
    const unsigned a0 = (unsigned)__shfl((int)W0, sa, 64);
    const unsigned a1 = (unsigned)__shfl((int)W1, sa, 64);
    const unsigned a2 = (unsigned)__shfl((int)W0, sb, 64);
    const unsigned a3 = (unsigned)__shfl((int)W1, sb, 64);
    const unsigned b0 = (unsigned)__shfl((int)W2, sa, 64);
    const unsigned b1 = (unsigned)__shfl((int)W3, sa, 64);
    const unsigned b2 = (unsigned)__shfl((int)W2, sb, 64);
    const unsigned b3 = (unsigned)__shfl((int)W3, sb, 64);
    out[0] = lo ? a0 : b0;
    out[1] = lo ? a1 : b1;
    out[2] = lo ? a2 : b2;
    out[3] = lo ? a3 : b3;
}

// ---------------- kernel 1: coor = relu(x@W1^T)@W2^T -> bf16 [N,32] ----------------
__global__ __launch_bounds__(256) void coor_kernel(
    const float* __restrict__ x, const float* __restrict__ w1,
    const float* __restrict__ w2, unsigned short* __restrict__ coorb, int N)
{
    __shared__ float sW1[96];
    __shared__ float sW2[1024];
    const int tid = threadIdx.x;
    if (tid < 96) sW1[tid] = w1[tid];
    for (int i = tid; i < 1024; i += 256) sW2[i] = w2[i];
    __syncthreads();
    int n = blockIdx.x * 256 + tid;
    if (n >= N) return;
    const float x0 = x[n*3+0], x1 = x[n*3+1], x2 = x[n*3+2];
    float h[32];
#pragma unroll
    for (int k = 0; k < 32; ++k)
        h[k] = fmaxf(sW1[k*3+0]*x0 + sW1[k*3+1]*x1 + sW1[k*3+2]*x2, 0.0f);
    union { uint4 q[4]; unsigned u[16]; } st;
#pragma unroll
    for (int p = 0; p < 16; ++p) {
        float a0 = 0.f, a1 = 0.f;
#pragma unroll
        for (int k = 0; k < 32; ++k) {
            a0 += sW2[(2*p)  *32 + k] * h[k];
            a1 += sW2[(2*p+1)*32 + k] * h[k];
        }
        st.u[p] = pack2(a0, a1);
    }
    uint4* cp = (uint4*)(coorb + (size_t)n * 32);
#pragma unroll
    for (int w = 0; w < 4; ++w) cp[w] = st.q[w];
}

// ---------------- kernel 2: MFMA bi-LSTM + message MLP + scatter ----------------
// One wave per 16-edge tile (TPW tiles serially). Transposed MFMA form:
//   gates[128 rows][16 edges] = [Whh|Wih+b] x [h;x;1]  per step, 16 mfma_16x16x32_bf16.
// Lane l = (q=l>>4, e=l&15): D gives lane gates for edge e, units {4q+r, 16+4q+r}.
__global__ __launch_bounds__(256, 2) void lstm_msg_kernel(
    const float* __restrict__ edge_traj,
    const float* __restrict__ w_ih_f, const float* __restrict__ w_hh_f,
    const float* __restrict__ b_ih_f, const float* __restrict__ b_hh_f,
    const float* __restrict__ w_ih_b, const float* __restrict__ w_hh_b,
    const float* __restrict__ b_ih_b, const float* __restrict__ b_hh_b,
    const float* __restrict__ nn2_w1, const float* __restrict__ nn2_w2,
    const int* __restrict__ edge_index,
    const unsigned short* __restrict__ coorb,
    float* __restrict__ agg, int E)
{
    const int lane = threadIdx.x & 63;
    const int wid  = threadIdx.x >> 6;
    const int le   = lane & 15;
    const int lq   = lane >> 4;
    const int sa   = ((lq & 1) << 5) + le;   // shfl source A (q_s = 2*(q&1))
    const int sb   = sa + 16;                // shfl source B (q_s = 2*(q&1)+1)
    const bool lo  = (lq < 2);               // target-side lo/hi word select
    const f32x4 Z4 = {0.f, 0.f, 0.f, 0.f};

    // ---- resident weight fragments (bf16) ----
    bf16x8 whf[8], whb[8], wxf[8], wxb[8];
#pragma unroll
    for (int m = 0; m < 8; ++m) {
        const int row = 16*m + le;
        whf[m] = ldw8(w_hh_f + row*32 + 8*lq);
        whb[m] = ldw8(w_hh_b + row*32 + 8*lq);
        wxf[m] = ldih(w_ih_f, b_ih_f, b_hh_f, row, lq);
        wxb[m] = ldih(w_ih_b, b_ih_b, b_hh_b, row, lq);
    }
    bf16x8 w1a[2][3], w2a[2];
#pragma unroll
    for (int mm = 0; mm < 2; ++mm) {
        const int row = 16*mm + le;
#pragma unroll
        for (int kc = 0; kc < 3; ++kc)
            w1a[mm][kc] = ldw8(nn2_w1 + row*96 + 32*kc + 8*lq);
        w2a[mm] = ldw8(nn2_w2 + row*32 + 8*lq);
    }

    const long gw = (long)blockIdx.x * 4 + wid;
    for (int it = 0; it < TPW; ++it) {
        const long tile = gw * TPW + it;
        const long e0 = tile * 16;
        if (e0 >= E) break;
        const long e_raw = e0 + le;
        const bool valid = e_raw < E;
        const long ec = valid ? e_raw : (E - 1);
        const float* xb = edge_traj + ec * 48;

        float tr_lo[4], tr_hi[4];   // traj encoding accumulation
        float cf_lo[4], cf_hi[4];
        for (int dir = 0; dir < 2; ++dir) {
            const bf16x8* wh = dir ? whb : whf;
            const bf16x8* wx = dir ? wxb : wxf;
            U4 hf; hf.u[0] = hf.u[1] = hf.u[2] = hf.u[3] = 0u;
            float c_lo[4] = {0,0,0,0}, c_hi[4] = {0,0,0,0};
            for (int t = 0; t < 8; ++t) {
                const int te = dir ? (7 - t) : t;
                U4 xf; xf.u[0] = xf.u[1] = xf.u[2] = xf.u[3] = 0u;
                if (lq == 0) {
                    const float* xp = xb + te * 6;
                    const float2 a  = *(const float2*)xp;
                    const float2 b2 = *(const float2*)(xp + 2);
                    const float2 c2 = *(const float2*)(xp + 4);
                    xf.u[0] = pack2(a.x, a.y);
                    xf.u[1] = pack2(b2.x, b2.y);
                    xf.u[2] = pack2(c2.x, c2.y);
                    xf.u[3] = 0x3f80u;              // k=6 -> 1.0 (bias), k=7 -> 0
                }
                f32x4 acc[8];
#pragma unroll
                for (int m = 0; m < 8; ++m)
                    acc[m] = __builtin_amdgcn_mfma_f32_16x16x32_bf16(wx[m], xf.v, Z4, 0, 0, 0);
#pragma unroll
                for (int m = 0; m < 8; ++m)
                    acc[m] = __builtin_amdgcn_mfma_f32_16x16x32_bf16(wh[m], hf.v, acc[m], 0, 0, 0);
                // gate tiles: m=0/1 -> i(lo/hi), 2/3 -> f, 4/5 -> g, 6/7 -> o
                float h_lo[4], h_hi[4];
#pragma unroll
                for (int r = 0; r < 4; ++r) {
                    float ig = sigm_(acc[0][r]);
                    float fg = sigm_(acc[2][r]);
                    float gg = tanh_(acc[4][r]);
                    float og = sigm_(acc[6][r]);
                    c_lo[r] = fg * c_lo[r] + ig * gg;
                    h_lo[r] = og * tanh_(c_lo[r]);
                    ig = sigm_(acc[1][r]);
                    fg = sigm_(acc[3][r]);
                    gg = tanh_(acc[5][r]);
                    og = sigm_(acc[7][r]);
                    c_hi[r] = fg * c_hi[r] + ig * gg;
                    h_hi[r] = og * tanh_(c_hi[r]);
                }
                redist(pack2(h_lo[0], h_lo[1]), pack2(h_lo[2], h_lo[3]),
                       pack2(h_hi[0], h_hi[1]), pack2(h_hi[2], h_hi[3]),
                       sa, sb, lo, hf.u);
            }
            if (dir == 0) {
#pragma unroll
                for (int r = 0; r < 4; ++r) { cf_lo[r] = c_lo[r]; cf_hi[r] = c_hi[r]; }
            } else {
#pragma unroll
                for (int r = 0; r < 4; ++r) {
                    tr_lo[r] = 0.5f * (cf_lo[r] + c_lo[r]);
                    tr_hi[r] = 0.5f * (cf_hi[r] + c_hi[r]);
                }
            }
        }

        // ---- message MLP: hidden = relu(W1 @ [coor_dst; coor_src; traj]) ; out = W2 @ hidden
        const int src = edge_index[ec];
        const int dst = edge_index[E + ec];
        U4 df, sf;
        {
            const uint4 dv = *(const uint4*)(coorb + (size_t)dst*32 + lq*8);
            const uint4 sv = *(const uint4*)(coorb + (size_t)src*32 + lq*8);
            df.u[0]=dv.x; df.u[1]=dv.y; df.u[2]=dv.z; df.u[3]=dv.w;
            sf.u[0]=sv.x; sf.u[1]=sv.y; sf.u[2]=sv.z; sf.u[3]=sv.w;
        }
        U4 tf;
        redist(pack2(tr_lo[0], tr_lo[1]), pack2(tr_lo[2], tr_lo[3]),
               pack2(tr_hi[0], tr_hi[1]), pack2(tr_hi[2], tr_hi[3]),
               sa, sb, lo, tf.u);

        f32x4 h1[2];
#pragma unroll
        for (int mm = 0; mm < 2; ++mm) {
            f32x4 a = __builtin_amdgcn_mfma_f32_16x16x32_bf16(w1a[mm][0], df.v, Z4, 0, 0, 0);
            a = __builtin_amdgcn_mfma_f32_16x16x32_bf16(w1a[mm][1], sf.v, a, 0, 0, 0);
            a = __builtin_amdgcn_mfma_f32_16x16x32_bf16(w1a[mm][2], tf.v, a, 0, 0, 0);
            h1[mm] = a;
        }
        U4 gf;
        redist(pack2(fmaxf(h1[0][0],0.f), fmaxf(h1[0][1],0.f)),
               pack2(fmaxf(h1[0][2],0.f), fmaxf(h1[0][3],0.f)),
               pack2(fmaxf(h1[1][0],0.f), fmaxf(h1[1][1],0.f)),
               pack2(fmaxf(h1[1][2],0.f), fmaxf(h1[1][3],0.f)),
               sa, sb, lo, gf.u);

        if (valid) {
#pragma unroll
            for (int mm = 0; mm < 2; ++mm) {
                const f32x4 o = __builtin_amdgcn_mfma_f32_16x16x32_bf16(w2a[mm], gf.v, Z4, 0, 0, 0);
#pragma unroll
                for (int r = 0; r < 4; ++r)
                    atomicAdd(agg + (size_t)dst*32 + (16*mm + 4*lq + r), o[r]);
            }
        } else {
#pragma unroll
            for (int mm = 0; mm < 2; ++mm) {
                const f32x4 o = __builtin_amdgcn_mfma_f32_16x16x32_bf16(w2a[mm], gf.v, Z4, 0, 0, 0);
                (void)o;
            }
        }
    }
}

// ---------------- kernel 3: s32[k] = sum_n relu(agg[n]@nn_w1^T)[k] ----------------
__global__ __launch_bounds__(256) void agg_kernel(
    const float* __restrict__ agg, const float* __restrict__ nn_w1,
    float* __restrict__ s32, int N)
{
    __shared__ float sW[1024];
    const int tid = threadIdx.x;
    for (int i = tid; i < 1024; i += 256) sW[i] = nn_w1[i];
    __syncthreads();
    const int n = blockIdx.x*256 + tid;
    float h[32];
    if (n < N) {
        float a[32];
        const float4* ap = (const float4*)(agg + (size_t)n*32);
#pragma unroll
        for (int k4 = 0; k4 < 8; ++k4) {
            const float4 v = ap[k4];
            a[k4*4]=v.x; a[k4*4+1]=v.y; a[k4*4+2]=v.z; a[k4*4+3]=v.w;
        }
#pragma unroll
        for (int jj = 0; jj < 32; ++jj) {
            float acc = 0.f;
#pragma unroll
            for (int k = 0; k < 32; ++k) acc += sW[jj*32+k]*a[k];
            h[jj] = fmaxf(acc, 0.f);
        }
    } else {
#pragma unroll
        for (int jj = 0; jj < 32; ++jj) h[jj] = 0.f;
    }
#pragma unroll
    for (int m = 1; m < 64; m <<= 1) {
#pragma unroll
        for (int k = 0; k < 32; ++k) h[k] += __shfl_xor(h[k], m, 64);
    }
    if ((tid & 63) == 0) {
#pragma unroll
        for (int k = 0; k < 32; ++k) atomicAdd(s32 + k, h[k]);
    }
}

// ---------------- kernel 4: out[o] = nn_w2[o,:] . s32 ----------------
__global__ void final_kernel(const float* __restrict__ nn_w2,
                             const float* __restrict__ s32, float* __restrict__ out)
{
    const int o = threadIdx.x;   // 64
    float acc = 0.f;
#pragma unroll
    for (int k = 0; k < 32; ++k) acc += nn_w2[o*32+k] * s32[k];
    out[o] = acc;
}

extern "C" void kernel_launch(void* const* d_in, const int* in_sizes, int n_in,
                              void* d_out, int out_size, void* d_ws, size_t ws_size,
                              hipStream_t stream)
{
    const float* x         = (const float*)d_in[0];
    const float* edge_traj = (const float*)d_in[1];
    const float* w_ih_f    = (const float*)d_in[2];
    const float* w_hh_f    = (const float*)d_in[3];
    const float* b_ih_f    = (const float*)d_in[4];
    const float* b_hh_f    = (const float*)d_in[5];
    const float* w_ih_b    = (const float*)d_in[6];
    const float* w_hh_b    = (const float*)d_in[7];
    const float* b_ih_b    = (const float*)d_in[8];
    const float* b_hh_b    = (const float*)d_in[9];
    const float* coor_w1   = (const float*)d_in[10];
    const float* coor_w2   = (const float*)d_in[11];
    const float* nn2_w1    = (const float*)d_in[12];
    const float* nn2_w2    = (const float*)d_in[13];
    const float* nn_w1     = (const float*)d_in[14];
    const float* nn_w2     = (const float*)d_in[15];
    const int* edge_index  = (const int*)d_in[16];
    const int N = in_sizes[0] / 3;
    const int E = in_sizes[16] / 2;

    float* agg = (float*)d_ws;
    float* s32 = agg + (size_t)N * 32;
    unsigned short* coorb = (unsigned short*)(s32 + 64);

    (void)hipMemsetAsync(agg, 0, ((size_t)N*32 + 64) * sizeof(float), stream);

    coor_kernel<<<(N + 255)/256, 256, 0, stream>>>(x, coor_w1, coor_w2, coorb, N);

    const long tiles  = ((long)E + 15) / 16;
    const long waves  = (tiles + TPW - 1) / TPW;
    const int  blocks = (int)((waves + 3) / 4);
    lstm_msg_kernel<<<blocks, 256, 0, stream>>>(edge_traj,
        w_ih_f, w_hh_f, b_ih_f, b_hh_f,
        w_ih_b, w_hh_b, b_ih_b, b_hh_b,
        nn2_w1, nn2_w2, edge_index, coorb, agg, E);

    agg_kernel<<<(N + 255)/256, 256, 0, stream>>>(agg, nn_w1, s32, N);
    final_kernel<<<1, 64, 0, stream>>>(nn_w2, s32, (float*)d_out);
}